// Round 2
// baseline (273.885 us; speedup 1.0000x reference)
//
#include <hip/hip_runtime.h>

// HausdorffDTLoss: exact separable EDT (fg & bg) per image, then
// mean((pred-target)^2 * (pred_dt^2 + target_dt^2)).
// Envelope identity: g[i] = min_j f[j]+(i-j)^2 = i^2 + min_j (h[j]-2ij),
// h[j]=f[j]+j^2. All intermediates are integers, |val| < 2^17 -> u16 storage,
// fp32 math exact (R1-R10: absmax 0.0).
//
// R11 vs R10 (249us, zy=120us, VALUBusy~93%, VGPR_Count=16 degenerate):
// theory -- allocator parks acc[16] in AGPRs (16 arch VGPRs only), paying
// accvgpr shuffles per min, and the fminf/fminf pair doesn't fuse to
// v_min3_f32. Fix at instruction level, not allocator-hint level:
//   (a) inline-asm v_min3_f32 with "+v"/"v" constraints -- 1 op for the
//       2-min pair AND forces acc/c into arch VGPRs (asm "v" can't bind AGPR);
//   (b) (c0,c1) and (jm2,jb) as float2 ext-vectors so the chain update is a
//       single v_pk_add_f32 (CDNA packed fp32).
// Inner step: 4 ops/k (-> ~7 with shuffles) becomes 2 ops/k. Exact math
// unchanged (min3 is an exact min; adds are integer-valued fp32).
// (R11 resubmit: previous run died in container acquisition, kernel never ran.)

constexpr int BIGI = 49153;      // 3*128^2+1, matches reference BIG exactly
constexpr int NVOX = 4194304;    // voxels per tensor (2 samples x 128^3)
constexpr int STZ  = 129;        // zy dword row stride: 129%32=1 -> 2-way max (free)
constexpr int STX  = 65;         // xloss dword row stride: same property

typedef float v2f __attribute__((ext_vector_type(2)));

__global__ void zero_kernel(float* out, int* flags) {
    out[0] = 0.0f;
    flags[0] = 0; flags[1] = 0; flags[2] = 0; flags[3] = 0;
}

// 64-pair (128-candidate) lower-envelope accumulation into acc[16] at
// outputs i0..i0+15. p points at column c of a [65*stride] u32 LDS array of
// packed u16 h-values; row 64 is slack for the 1-ahead prefetch.
// Inner loop: v_min3_f32 (asm, forces arch VGPRs) + v_pk_add_f32 chain.
__device__ __forceinline__ void envelope64(const unsigned int* __restrict__ p,
                                           const int stride, const float i0f,
                                           float acc[16]) {
    unsigned int vc = p[0];
    v2f jv; jv.x = 0.0f; jv.y = -2.0f;     // (-2*(2q), -2*(2q+1))
    v2f m4; m4.x = -4.0f; m4.y = -4.0f;
    for (int q = 0; q < 64; ++q) {
        unsigned int vn = p[(q + 1) * stride];   // 1-pair prefetch (row 64 slack)
        v2f c;
        c.x = fmaf(jv.x, i0f, (float)(vc & 0xffffu));  // cand at i=i0, y=2q
        c.y = fmaf(jv.y, i0f, (float)(vc >> 16));      // cand at i=i0, y=2q+1
#pragma unroll
        for (int k = 0; k < 16; ++k) {
            // acc[k] = min(acc[k], c.x, c.y) -- single VOP3, arch-VGPR forced
            asm("v_min3_f32 %0, %0, %1, %2"
                : "+v"(acc[k]) : "v"(c.x), "v"(c.y));
            c += jv;                         // v_pk_add_f32: exact, |.|<2^17
        }
        jv += m4;
        vc = vn;
    }
}

// Fused binarize + parallel bitmask z-EDT + y-envelope for one (b,x) slab of
// one image, one polarity. 512 thr, 35.8KB LDS, 4 blocks/CU.
__global__ __launch_bounds__(512) void zy_kernel(const float* __restrict__ pred,
                                                 const float* __restrict__ tgt,
                                                 unsigned short* __restrict__ ws,
                                                 int* __restrict__ flags) {
    __shared__ unsigned int hz[65 * STZ];          // packed u16 pairs: (y-pair, z)
    __shared__ unsigned long long bm[256];         // site bitmasks: [y][z-half]
    const int t   = blockIdx.x;
    const int pol = t & 1;                         // 0: fg EDT (sites=~fg), 1: bg
    const int img = (t >> 1) & 1;
    const int s   = t >> 2;                        // 0..255: b(2) x x(128)
    const int b   = s >> 7;
    const int x   = s & 127;
    const int sb  = (b * 128 + x) * 16384;         // + y*128 + z
    const int tid = threadIdx.x;
    const float* im = img ? tgt : pred;

    // ---- stage: coalesced read -> per-wave ballot -> site bitmasks ----
    bool anyfg = false;
#pragma unroll
    for (int k = 0; k < 32; ++k) {
        int l = tid + k * 512;
        float v = im[sb + l];
        bool fg = v > 0.5f;
        anyfg |= fg;
        bool site = pol ? fg : !fg;
        unsigned long long bal = __ballot(site);
        if ((tid & 63) == 0) bm[l >> 6] = bal;     // l>>6 uniform per wave
    }
    if (!pol && __ballot(anyfg) != 0ULL && (tid & 63) == 0)
        atomicOr(flags + img * 2 + b, 1);
    __syncthreads();

    // ---- parallel z-EDT: per-voxel nearest-site distance from the masks ----
    unsigned short* hu = (unsigned short*)hz;
    const int z = tid & 127;                       // fixed per thread, uniform/wave
#pragma unroll
    for (int k = 0; k < 32; ++k) {
        int y = (tid >> 7) + k * 4;
        unsigned long long m0 = bm[2 * y], m1 = bm[2 * y + 1];
        int d;
        if (z < 64) {
            unsigned long long lm = m0 << (63 - z);
            unsigned long long rm = m0 >> z;
            int dfwd = lm ? __builtin_clzll(lm) : 999;
            int db0  = rm ? __builtin_ctzll(rm) : 999;
            int db1  = (m1 ? __builtin_ctzll(m1) : 999) + (64 - z);
            d = min(dfwd, min(db0, db1));
        } else {
            int zz = z - 64;
            unsigned long long lm = m1 << (63 - zz);
            unsigned long long rm = m1 >> zz;
            int df1 = lm ? __builtin_clzll(lm) : 999;
            int df0 = (m0 ? __builtin_clzll(m0) : 999) + zz + 1;
            int dbw = rm ? __builtin_ctzll(rm) : 999;
            d = min(min(df1, df0), dbw);
        }
        int f = (d <= 127) ? d * d : BIGI;         // empty line -> BIG (exact)
        hu[((y >> 1) * STZ) * 2 + (y & 1) + 2 * z] = (unsigned short)(f + y * y);
    }
    __syncthreads();

    // ---- y-envelope: c = z column, 4 groups, two SEQUENTIAL i-rounds ----
    unsigned short* outv = ws + (size_t)(img * 2 + pol) * NVOX + sb;
    const int c = tid & 127;
#pragma clang loop unroll(disable)
    for (int r = 0; r < 2; ++r) {                  // one acc[16] set live at a time
        const int i0 = (tid >> 7) * 16 + r * 64;
        const float i0f = (float)i0;
        float acc[16];
#pragma unroll
        for (int k = 0; k < 16; ++k) acc[k] = 3.0e38f;
        envelope64(hz + c, STZ, i0f, acc);
#pragma unroll
        for (int k = 0; k < 16; ++k) {             // gy = acc + y^2 <= 49153: u16
            float iif = i0f + (float)k;
            outv[(i0 + k) * 128 + c] = (unsigned short)(unsigned int)fmaf(iif, iif, acc[k]);
        }
    }
}

// X-envelope for A and B + fused loss partial (R8 structure, min3/pk inner).
// Tile: 64 (y,z) columns x 128 x of one sample of one image. 512 thr, 16.9KB LDS.
__global__ __launch_bounds__(512) void xloss_kernel(const float* __restrict__ pred,
                                                    const float* __restrict__ tgt,
                                                    const unsigned short* __restrict__ ws,
                                                    const int* __restrict__ flags,
                                                    float* __restrict__ out) {
    __shared__ unsigned int hx[65 * STX];
    __shared__ float red[8];
    const int t    = blockIdx.x;
    const int img  = t & 1;                    // adjacent blocks share pred/tgt chunk
    const int b    = (t >> 1) & 1;
    const int q0   = (t >> 2) * 64;
    const int base = b * 2097152 + q0;         // + x*16384 + c
    const int tid  = threadIdx.x;
    const int c    = tid & 63;
    const int i0   = (tid >> 6) * 16;
    const float i0f = (float)i0;
    unsigned short* hu = (unsigned short*)hx;
    const unsigned short* A16 = ws + (size_t)(img * 2) * NVOX;
    const unsigned short* B16 = A16 + NVOX;
    float accA[16], accB[16];

    // ---- stage + envelope A ----
#pragma unroll
    for (int k = 0; k < 16; ++k) {
        int l = tid + k * 512;
        int cc = l & 63, j = l >> 6;
        unsigned int v = A16[base + j * 16384 + cc];
        hu[((j >> 1) * STX + cc) * 2 + (j & 1)] = (unsigned short)(v + j * j); // <=65282
    }
    __syncthreads();
    {
#pragma unroll
        for (int k = 0; k < 16; ++k) accA[k] = 3.0e38f;
        envelope64(hx + c, STX, i0f, accA);
    }
    __syncthreads();

    // ---- stage + envelope B ----
#pragma unroll
    for (int k = 0; k < 16; ++k) {
        int l = tid + k * 512;
        int cc = l & 63, j = l >> 6;
        unsigned int v = B16[base + j * 16384 + cc];
        hu[((j >> 1) * STX + cc) * 2 + (j & 1)] = (unsigned short)(v + j * j);
    }
    __syncthreads();
    {
#pragma unroll
        for (int k = 0; k < 16; ++k) accB[k] = 3.0e38f;
        envelope64(hx + c, STX, i0f, accB);
    }

    // ---- loss partial: (p-t)^2 * (sqrt(gA)+sqrt(gB))^2 * guard ----
    float s = 0.0f;
#pragma unroll
    for (int k = 0; k < 16; ++k) {
        float iif = i0f + (float)k;
        float gA = fmaf(iif, iif, accA[k]);
        float gB = fmaf(iif, iif, accB[k]);
        int v = base + (i0 + k) * 16384 + c;     // coalesced across c per k
        float d = pred[v] - tgt[v];
        float fld = sqrtf(gA) + sqrtf(gB);
        s += d * d * fld * fld;
    }
    if (!flags[img * 2 + b]) s = 0.0f;
#pragma unroll
    for (int off = 32; off > 0; off >>= 1) s += __shfl_down(s, off);
    if ((tid & 63) == 0) red[tid >> 6] = s;
    __syncthreads();
    if (tid == 0) {
        float tot = 0.0f;
#pragma unroll
        for (int w = 0; w < 8; ++w) tot += red[w];
        atomicAdd(out, tot * (1.0f / 4194304.0f));
    }
}

extern "C" void kernel_launch(void* const* d_in, const int* in_sizes, int n_in,
                              void* d_out, int out_size, void* d_ws, size_t ws_size,
                              hipStream_t stream) {
    const float* pred = (const float*)d_in[0];
    const float* tgt  = (const float*)d_in[1];
    float* out = (float*)d_out;
    unsigned short* ws16 = (unsigned short*)d_ws;  // 4 u16 volumes = 33.6 MB
    int* flags = (int*)(ws16 + 4 * (size_t)NVOX);  // [img0_b0, img0_b1, img1_b0, img1_b1]

    zero_kernel<<<1, 1, 0, stream>>>(out, flags);
    zy_kernel<<<dim3(1024), 512, 0, stream>>>(pred, tgt, ws16, flags);
    xloss_kernel<<<dim3(1024), 512, 0, stream>>>(pred, tgt, ws16, flags, out);
}

// Round 3
// 187.952 us; speedup vs baseline: 1.4572x; 1.4572x over previous
//
#include <hip/hip_runtime.h>

// HausdorffDTLoss: exact separable EDT (fg & bg) per image, then
// mean((pred-target)^2 * (pred_dt^2 + target_dt^2)).
// Envelope identity: g[i] = min_j f[j]+(i-j)^2 = i^2 + min_j (h[j]-2ij),
// h[j]=f[j]+j^2. All intermediates are integers, |val| < 2^17 -> u16 storage,
// fp32 math exact (R1-R10: absmax 0.0).
//
// R12: R11's asm min3 + packed chain REGRESSED (zy 120->134us, VALUBusy
// 93->61%): opaque asm + single serial pk-add chain = latency-stalled, and
// VGPR_Count stayed 16 (VALU reads AGPRs directly on CDNA; no shuffle tax
// existed). Reverted inner loop to R10 form (proven 93% issue-bound).
// NEW: exact candidate windowing. g(i) <= f(i) (candidate j=i), so any j
// with (i-j)^2 >= f(i) cannot win -> scan only |i-j| <= W,
// W = ceil(sqrt(max f over wave's outputs)), wave-uniform via shfl-max +
// readfirstlane (SGPR loop bounds, no divergence). Exact for ANY input;
// for Bernoulli(1/2) masks W~5 -> q-loop 64 -> ~14 pairs (~4.5x fewer ops).
// Worst case (empty line, f=BIG) falls back to the full scan.

constexpr int BIGI = 49153;      // 3*128^2+1, matches reference BIG exactly
constexpr int NVOX = 4194304;    // voxels per tensor (2 samples x 128^3)
constexpr int STZ  = 129;        // zy dword row stride: 129%32=1 -> 2-way max (free)
constexpr int STX  = 65;         // xloss dword row stride: same property

__global__ void zero_kernel(float* out, int* flags) {
    out[0] = 0.0f;
    flags[0] = 0; flags[1] = 0; flags[2] = 0; flags[3] = 0;
}

// Windowed 128-candidate lower-envelope accumulation into acc[16] at outputs
// i0..i0+15. p = column c of a [65*stride] u32 LDS array of packed u16
// h-values (row 64 = prefetch slack). Window: only pairs q in [qlo,qhi]
// (SGPR-uniform) are scanned; caller guarantees every candidate that can win
// lies inside. Inner loop = R10 form: 2 independent fp32 chains + fminf pairs.
__device__ __forceinline__ void envelope_win(const unsigned int* __restrict__ p,
                                             const int stride, const float i0f,
                                             const int qlo, const int qhi,
                                             float acc[16]) {
    unsigned int vc = p[qlo * stride];
    float jm2 = -4.0f * (float)qlo;            // -2*(2q)
    for (int q = qlo; q <= qhi; ++q) {
        unsigned int vn = p[(q + 1) * stride]; // 1-pair prefetch (slack row)
        float h0 = (float)(vc & 0xffffu);      // y = 2q
        float h1 = (float)(vc >> 16);          // y = 2q+1
        float jb = jm2 - 2.0f;
        float c0 = fmaf(jm2, i0f, h0);         // candidate at i = i0
        float c1 = fmaf(jb,  i0f, h1);
#pragma unroll
        for (int k = 0; k < 16; ++k) {
            acc[k] = fminf(acc[k], fminf(c0, c1));
            c0 += jm2; c1 += jb;               // exact: integers < 2^17
        }
        jm2 -= 4.0f;
        vc = vn;
    }
}

// Compute wave-uniform window W from the thread's own 16 f-values
// (f = h - i^2), wave-maxed. W*W >= fmax guaranteed (ceil-sqrt with fixup).
__device__ __forceinline__ int window_of(const unsigned int* __restrict__ p,
                                         const int stride, const int i0) {
    int fmx = 0;
#pragma unroll
    for (int m = 0; m < 8; ++m) {
        unsigned int v = p[((i0 >> 1) + m) * stride];
        int y0 = i0 + 2 * m, y1 = y0 + 1;
        int f0 = (int)(v & 0xffffu) - y0 * y0;
        int f1 = (int)(v >> 16) - y1 * y1;
        fmx = max(fmx, max(f0, f1));
    }
#pragma unroll
    for (int off = 32; off; off >>= 1) fmx = max(fmx, __shfl_xor(fmx, off));
    int W = (int)sqrtf((float)fmx);            // fmx <= 49153, exact in fp32
    W += (W * W < fmx);
    W += (W * W < fmx);                        // guarantees W*W >= fmx
    return W;
}

// Fused binarize + parallel bitmask z-EDT + windowed y-envelope for one (b,x)
// slab of one image, one polarity. 512 thr, 35.8KB LDS, 4 blocks/CU.
__global__ __launch_bounds__(512) void zy_kernel(const float* __restrict__ pred,
                                                 const float* __restrict__ tgt,
                                                 unsigned short* __restrict__ ws,
                                                 int* __restrict__ flags) {
    __shared__ unsigned int hz[65 * STZ];          // packed u16 pairs: (y-pair, z)
    __shared__ unsigned long long bm[256];         // site bitmasks: [y][z-half]
    const int t   = blockIdx.x;
    const int pol = t & 1;                         // 0: fg EDT (sites=~fg), 1: bg
    const int img = (t >> 1) & 1;
    const int s   = t >> 2;                        // 0..255: b(2) x x(128)
    const int b   = s >> 7;
    const int x   = s & 127;
    const int sb  = (b * 128 + x) * 16384;         // + y*128 + z
    const int tid = threadIdx.x;
    const float* im = img ? tgt : pred;

    // ---- stage: coalesced read -> per-wave ballot -> site bitmasks ----
    bool anyfg = false;
#pragma unroll
    for (int k = 0; k < 32; ++k) {
        int l = tid + k * 512;
        float v = im[sb + l];
        bool fg = v > 0.5f;
        anyfg |= fg;
        bool site = pol ? fg : !fg;
        unsigned long long bal = __ballot(site);
        if ((tid & 63) == 0) bm[l >> 6] = bal;     // l>>6 uniform per wave
    }
    if (!pol && __ballot(anyfg) != 0ULL && (tid & 63) == 0)
        atomicOr(flags + img * 2 + b, 1);
    __syncthreads();

    // ---- parallel z-EDT: per-voxel nearest-site distance from the masks ----
    unsigned short* hu = (unsigned short*)hz;
    const int z = tid & 127;                       // fixed per thread, uniform/wave
#pragma unroll
    for (int k = 0; k < 32; ++k) {
        int y = (tid >> 7) + k * 4;
        unsigned long long m0 = bm[2 * y], m1 = bm[2 * y + 1];
        int d;
        if (z < 64) {
            unsigned long long lm = m0 << (63 - z);
            unsigned long long rm = m0 >> z;
            int dfwd = lm ? __builtin_clzll(lm) : 999;
            int db0  = rm ? __builtin_ctzll(rm) : 999;
            int db1  = (m1 ? __builtin_ctzll(m1) : 999) + (64 - z);
            d = min(dfwd, min(db0, db1));
        } else {
            int zz = z - 64;
            unsigned long long lm = m1 << (63 - zz);
            unsigned long long rm = m1 >> zz;
            int df1 = lm ? __builtin_clzll(lm) : 999;
            int df0 = (m0 ? __builtin_clzll(m0) : 999) + zz + 1;
            int dbw = rm ? __builtin_ctzll(rm) : 999;
            d = min(min(df1, df0), dbw);
        }
        int f = (d <= 127) ? d * d : BIGI;         // empty line -> BIG (exact)
        hu[((y >> 1) * STZ) * 2 + (y & 1) + 2 * z] = (unsigned short)(f + y * y);
    }
    __syncthreads();

    // ---- y-envelope: c = z column, 4 groups, two SEQUENTIAL i-rounds ----
    unsigned short* outv = ws + (size_t)(img * 2 + pol) * NVOX + sb;
    const int c = tid & 127;
#pragma clang loop unroll(disable)
    for (int r = 0; r < 2; ++r) {                  // one acc[16] set live at a time
        const int i0 = (tid >> 7) * 16 + r * 64;   // wave-uniform
        const float i0f = (float)i0;
        const int W = window_of(hz + c, STZ, i0);
        const int qlo = __builtin_amdgcn_readfirstlane(max(0, (i0 - W) >> 1));
        const int qhi = __builtin_amdgcn_readfirstlane(min(63, (i0 + 15 + W) >> 1));
        float acc[16];
#pragma unroll
        for (int k = 0; k < 16; ++k) acc[k] = 3.0e38f;
        envelope_win(hz + c, STZ, i0f, qlo, qhi, acc);
#pragma unroll
        for (int k = 0; k < 16; ++k) {             // gy = acc + y^2 <= 49153: u16
            float iif = i0f + (float)k;
            outv[(i0 + k) * 128 + c] = (unsigned short)(unsigned int)fmaf(iif, iif, acc[k]);
        }
    }
}

// Windowed x-envelope for A and B + fused loss partial.
// Tile: 64 (y,z) columns x 128 x of one sample of one image. 512 thr, 16.9KB LDS.
__global__ __launch_bounds__(512) void xloss_kernel(const float* __restrict__ pred,
                                                    const float* __restrict__ tgt,
                                                    const unsigned short* __restrict__ ws,
                                                    const int* __restrict__ flags,
                                                    float* __restrict__ out) {
    __shared__ unsigned int hx[65 * STX];
    __shared__ float red[8];
    const int t    = blockIdx.x;
    const int img  = t & 1;                    // adjacent blocks share pred/tgt chunk
    const int b    = (t >> 1) & 1;
    const int q0   = (t >> 2) * 64;
    const int base = b * 2097152 + q0;         // + x*16384 + c
    const int tid  = threadIdx.x;
    const int c    = tid & 63;
    const int i0   = (tid >> 6) * 16;          // wave-uniform
    const float i0f = (float)i0;
    unsigned short* hu = (unsigned short*)hx;
    const unsigned short* A16 = ws + (size_t)(img * 2) * NVOX;
    const unsigned short* B16 = A16 + NVOX;
    float accA[16], accB[16];

    // ---- stage + envelope A ----
#pragma unroll
    for (int k = 0; k < 16; ++k) {
        int l = tid + k * 512;
        int cc = l & 63, j = l >> 6;
        unsigned int v = A16[base + j * 16384 + cc];
        hu[((j >> 1) * STX + cc) * 2 + (j & 1)] = (unsigned short)(v + j * j); // <=65282
    }
    __syncthreads();
    {
        const int W = window_of(hx + c, STX, i0);
        const int qlo = __builtin_amdgcn_readfirstlane(max(0, (i0 - W) >> 1));
        const int qhi = __builtin_amdgcn_readfirstlane(min(63, (i0 + 15 + W) >> 1));
#pragma unroll
        for (int k = 0; k < 16; ++k) accA[k] = 3.0e38f;
        envelope_win(hx + c, STX, i0f, qlo, qhi, accA);
    }
    __syncthreads();

    // ---- stage + envelope B ----
#pragma unroll
    for (int k = 0; k < 16; ++k) {
        int l = tid + k * 512;
        int cc = l & 63, j = l >> 6;
        unsigned int v = B16[base + j * 16384 + cc];
        hu[((j >> 1) * STX + cc) * 2 + (j & 1)] = (unsigned short)(v + j * j);
    }
    __syncthreads();
    {
        const int W = window_of(hx + c, STX, i0);
        const int qlo = __builtin_amdgcn_readfirstlane(max(0, (i0 - W) >> 1));
        const int qhi = __builtin_amdgcn_readfirstlane(min(63, (i0 + 15 + W) >> 1));
#pragma unroll
        for (int k = 0; k < 16; ++k) accB[k] = 3.0e38f;
        envelope_win(hx + c, STX, i0f, qlo, qhi, accB);
    }

    // ---- loss partial: (p-t)^2 * (sqrt(gA)+sqrt(gB))^2 * guard ----
    float s = 0.0f;
#pragma unroll
    for (int k = 0; k < 16; ++k) {
        float iif = i0f + (float)k;
        float gA = fmaf(iif, iif, accA[k]);
        float gB = fmaf(iif, iif, accB[k]);
        int v = base + (i0 + k) * 16384 + c;     // coalesced across c per k
        float d = pred[v] - tgt[v];
        float fld = sqrtf(gA) + sqrtf(gB);
        s += d * d * fld * fld;
    }
    if (!flags[img * 2 + b]) s = 0.0f;
#pragma unroll
    for (int off = 32; off > 0; off >>= 1) s += __shfl_down(s, off);
    if ((tid & 63) == 0) red[tid >> 6] = s;
    __syncthreads();
    if (tid == 0) {
        float tot = 0.0f;
#pragma unroll
        for (int w = 0; w < 8; ++w) tot += red[w];
        atomicAdd(out, tot * (1.0f / 4194304.0f));
    }
}

extern "C" void kernel_launch(void* const* d_in, const int* in_sizes, int n_in,
                              void* d_out, int out_size, void* d_ws, size_t ws_size,
                              hipStream_t stream) {
    const float* pred = (const float*)d_in[0];
    const float* tgt  = (const float*)d_in[1];
    float* out = (float*)d_out;
    unsigned short* ws16 = (unsigned short*)d_ws;  // 4 u16 volumes = 33.6 MB
    int* flags = (int*)(ws16 + 4 * (size_t)NVOX);  // [img0_b0, img0_b1, img1_b0, img1_b1]

    zero_kernel<<<1, 1, 0, stream>>>(out, flags);
    zy_kernel<<<dim3(1024), 512, 0, stream>>>(pred, tgt, ws16, flags);
    xloss_kernel<<<dim3(1024), 512, 0, stream>>>(pred, tgt, ws16, flags, out);
}